// Round 5
// baseline (712.588 us; speedup 1.0000x reference)
//
#include <hip/hip_runtime.h>

typedef __bf16 bf16x8 __attribute__((ext_vector_type(8)));
typedef __bf16 bf16x4 __attribute__((ext_vector_type(4)));
typedef float f32x4 __attribute__((ext_vector_type(4)));

#define T_DIM 1024
#define D_DIM 128
#define NHEAD 64

static constexpr float INV_TEMP = 0.08838834764831845f; // 1/sqrt(128)
static constexpr size_t OUT_ATTN = (size_t)NHEAD * T_DIM * D_DIM;            // 8388608
static constexpr size_t OUT_AF = OUT_ATTN + (size_t)NHEAD * T_DIM * T_DIM;   // 75497472

#define MFMA16 __builtin_amdgcn_mfma_f32_16x16x32_bf16

// XOR-swizzled pitch-128 LDS layout: 8-element chunks permuted by row to avoid
// bank conflicts without padding.
__device__ __forceinline__ int swz(int row, int col) {
  return (row << 7) + ((((col >> 3) ^ row) & 15) << 3) + (col & 7);
}

__device__ __forceinline__ bf16x8 ld8(const __bf16* buf, int row, int col) {
  return *reinterpret_cast<const bf16x8*>(&buf[swz(row, col)]);
}

// NT store helper using a clang ext_vector (HIP float4 is a class and is
// rejected by __builtin_nontemporal_store).
__device__ __forceinline__ void nt_store4(float* dst, float a, float b, float c, float d) {
  f32x4 v = {a, b, c, d};
  __builtin_nontemporal_store(v, reinterpret_cast<f32x4*>(dst));
}

// Stage a contiguous 128x128 fp32 tile (row stride 128 floats) into swizzled bf16 LDS.
// (256-thread kernels only.)
__device__ __forceinline__ void stage_f32_tile_128(const float* __restrict__ src,
                                                   __bf16* dst, int tid, float scale) {
  const float4* s4 = reinterpret_cast<const float4*>(src);
#pragma unroll
  for (int i = 0; i < 16; ++i) {
    int flat = i * 256 + tid;   // 0..4095 float4s
    int row = flat >> 5;
    int c4 = (flat & 31) << 2;
    float4 vq = s4[flat];
    bf16x4 b;
    b[0] = (__bf16)(vq.x * scale);
    b[1] = (__bf16)(vq.y * scale);
    b[2] = (__bf16)(vq.z * scale);
    b[3] = (__bf16)(vq.w * scale);
    *reinterpret_cast<bf16x4*>(&dst[swz(row, c4)]) = b;
  }
}

// Stage a 128x128 bf16 tile from WT (row stride T_DIM) into swizzled LDS (reg path,
// 256-thread fallback kernel).
__device__ __forceinline__ void stage_wt_tile(const __bf16* __restrict__ src,
                                              __bf16* dst, int tid) {
#pragma unroll
  for (int i = 0; i < 8; ++i) {
    int flat = i * 256 + tid;   // 0..2047 chunks of 8
    int row = flat >> 4;
    int c8 = (flat & 15) << 3;
    bf16x8 vv = *reinterpret_cast<const bf16x8*>(src + (size_t)row * T_DIM + c8);
    *reinterpret_cast<bf16x8*>(&dst[swz(row, c8)]) = vv;
  }
}

// ---- async (global_load_lds) staging: LDS written linearly by the DMA, the
// XOR swizzle is applied on the per-lane *source* address (m173 pattern), so
// ld8()/swz() readers are unchanged. 512-thread version: 4 instr/thread/tile.
__device__ __forceinline__ void cp16_async(const void* g, void* l) {
  typedef __attribute__((address_space(1))) unsigned int gu32;
  typedef __attribute__((address_space(3))) unsigned int lu32;
  __builtin_amdgcn_global_load_lds((gu32*)g, (lu32*)l, 16, 0, 0);
}

__device__ __forceinline__ void stage_async_tile512(const __bf16* __restrict__ gbase,
                                                    int row_stride_elems,
                                                    __bf16* lbuf, int tid) {
  const int w = tid >> 6;              // 0..7
  const int lane = tid & 63;
#pragma unroll
  for (int i = 0; i < 4; ++i) {
    int seg = i * 8 + w;               // 32 segments of 1 KiB
    int row = seg * 4 + (lane >> 4);   // 0..127
    int c = ((lane & 15) ^ row) & 15;  // pre-swizzled source chunk
    const void* src = (const void*)(gbase + (size_t)row * row_stride_elems + c * 8);
    void* dst = (void*)(lbuf + seg * 512);   // wave-uniform LDS base
    cp16_async(src, dst);
  }
}

// S = A(regs) * B(LDS): per-wave 32x128 tile, K=128.
__device__ __forceinline__ void compute_S(const bf16x8 afrag[4][2], const __bf16* bufB,
                                          int l16, int quad, f32x4 sacc[2][8]) {
#pragma unroll
  for (int mt = 0; mt < 2; ++mt)
#pragma unroll
    for (int nt = 0; nt < 8; ++nt)
      sacc[mt][nt] = (f32x4){0.f, 0.f, 0.f, 0.f};
#pragma unroll
  for (int ki = 0; ki < 4; ++ki) {
    bf16x8 bfr[8];
#pragma unroll
    for (int nt = 0; nt < 8; ++nt)
      bfr[nt] = ld8(bufB, nt * 16 + l16, ki * 32 + quad * 8);
#pragma unroll
    for (int nt = 0; nt < 8; ++nt) {
      sacc[0][nt] = MFMA16(afrag[ki][0], bfr[nt], sacc[0][nt], 0, 0, 0);
      sacc[1][nt] = MFMA16(afrag[ki][1], bfr[nt], sacc[1][nt], 0, 0, 0);
    }
  }
}

// ---------------------------------------------------------------------------
// KF: attn_feature[head][d][e] = softmax_e( sum_t qf[t][d]*kf[t][e] / TEMP )
// grid 128 = (2 d-halves) x 64 heads; block 256. LDS-transposed staging.
// ---------------------------------------------------------------------------
__global__ __launch_bounds__(256, 2)
void cd_attn_feature(const float* __restrict__ qf, const float* __restrict__ kf,
                     float* __restrict__ out) {
  __shared__ __bf16 qfT[64][40];    // [d][t] pitch 40 (80B rows, 16B aligned)
  __shared__ __bf16 kfT[128][40];   // [e][t]
  const int tid = threadIdx.x;
  const int w = tid >> 6;
  const int lane = tid & 63;
  const int quad = lane >> 4;
  const int l16 = lane & 15;
  const int head = blockIdx.x & 63;
  const int dstart = (blockIdx.x >> 6) << 6;

  const float* __restrict__ qfh = qf + (size_t)head * (T_DIM * D_DIM);
  const float* __restrict__ kfh = kf + (size_t)head * (T_DIM * D_DIM);

  f32x4 acc[8];
#pragma unroll
  for (int nt = 0; nt < 8; ++nt) acc[nt] = (f32x4){0.f, 0.f, 0.f, 0.f};

  for (int tc = 0; tc < T_DIM; tc += 32) {
    __syncthreads();
#pragma unroll
    for (int i = 0; i < 2; ++i) {          // qf chunk: 32 t x 64 d -> qfT
      int flat = i * 256 + tid;            // 0..511
      int t = flat >> 4;
      int d4 = (flat & 15) << 2;
      float4 vv = *reinterpret_cast<const float4*>(qfh + (size_t)(tc + t) * D_DIM + dstart + d4);
      qfT[d4 + 0][t] = (__bf16)vv.x;
      qfT[d4 + 1][t] = (__bf16)vv.y;
      qfT[d4 + 2][t] = (__bf16)vv.z;
      qfT[d4 + 3][t] = (__bf16)vv.w;
    }
#pragma unroll
    for (int i = 0; i < 4; ++i) {          // kf chunk: 32 t x 128 e -> kfT
      int flat = i * 256 + tid;            // 0..1023
      int t = flat >> 5;
      int e4 = (flat & 31) << 2;
      float4 vv = *reinterpret_cast<const float4*>(kfh + (size_t)(tc + t) * D_DIM + e4);
      kfT[e4 + 0][t] = (__bf16)vv.x;
      kfT[e4 + 1][t] = (__bf16)vv.y;
      kfT[e4 + 2][t] = (__bf16)vv.z;
      kfT[e4 + 3][t] = (__bf16)vv.w;
    }
    __syncthreads();
    bf16x8 a = *reinterpret_cast<const bf16x8*>(&qfT[w * 16 + l16][quad * 8]);
#pragma unroll
    for (int nt = 0; nt < 8; ++nt) {
      bf16x8 b = *reinterpret_cast<const bf16x8*>(&kfT[nt * 16 + l16][quad * 8]);
      acc[nt] = MFMA16(a, b, acc[nt], 0, 0, 0);
    }
  }

  float p[8][4];
  float rsum[4] = {0.f, 0.f, 0.f, 0.f};
#pragma unroll
  for (int nt = 0; nt < 8; ++nt)
#pragma unroll
    for (int r = 0; r < 4; ++r) {
      p[nt][r] = __expf(acc[nt][r] * INV_TEMP);
      rsum[r] += p[nt][r];
    }
#pragma unroll
  for (int off = 1; off < 16; off <<= 1)
#pragma unroll
    for (int r = 0; r < 4; ++r)
      rsum[r] += __shfl_xor(rsum[r], off, 64);
#pragma unroll
  for (int r = 0; r < 4; ++r) rsum[r] = 1.0f / rsum[r];

  float* __restrict__ afh = out + OUT_AF + (size_t)head * (D_DIM * D_DIM);
#pragma unroll
  for (int nt = 0; nt < 8; ++nt)
#pragma unroll
    for (int r = 0; r < 4; ++r)
      afh[(size_t)(dstart + w * 16 + quad * 4 + r) * D_DIM + nt * 16 + l16] = p[nt][r] * rsum[r];
}

// ---------------------------------------------------------------------------
// KW: W = V @ AF per head; store transposed WT[head][e][t] in bf16 (d_ws).
// Also absorbs the bf16 prep of qt/kt. grid 512 = 8 row-tiles x 64 heads.
// ---------------------------------------------------------------------------
__global__ __launch_bounds__(256, 2)
void cd_attn_w(const float* __restrict__ v, const float* __restrict__ out_ro,
               __bf16* __restrict__ wt,
               const float* __restrict__ qt, const float* __restrict__ kt,
               __bf16* __restrict__ qtb, __bf16* __restrict__ ktb) {
  __shared__ __bf16 vt[128 * 128];
  __shared__ __bf16 aft[128 * 128];   // aft[e][d]; reused as WT-tile bounce
  const int tid = threadIdx.x;
  const int w = tid >> 6;
  const int lane = tid & 63;
  const int quad = lane >> 4;
  const int l16 = lane & 15;
  const int head = blockIdx.x & 63;
  const int t0 = (blockIdx.x >> 6) << 7;

  // Fold-in of the former cd_prep: qtb = bf16(qt*INV_TEMP), ktb = bf16(kt).
  if (qtb != nullptr) {
    const float4* q4 = reinterpret_cast<const float4*>(qt);
    const float4* k4 = reinterpret_cast<const float4*>(kt);
    size_t base = (size_t)blockIdx.x * 2048 + tid;   // 512*2048*8 = 8388608 elems
#pragma unroll
    for (int i = 0; i < 8; ++i) {
      size_t c = base + (size_t)(i * 256);
      float4 a = q4[c * 2], b = q4[c * 2 + 1];
      bf16x8 o;
      o[0] = (__bf16)(a.x * INV_TEMP); o[1] = (__bf16)(a.y * INV_TEMP);
      o[2] = (__bf16)(a.z * INV_TEMP); o[3] = (__bf16)(a.w * INV_TEMP);
      o[4] = (__bf16)(b.x * INV_TEMP); o[5] = (__bf16)(b.y * INV_TEMP);
      o[6] = (__bf16)(b.z * INV_TEMP); o[7] = (__bf16)(b.w * INV_TEMP);
      *reinterpret_cast<bf16x8*>(qtb + c * 8) = o;
      a = k4[c * 2]; b = k4[c * 2 + 1];
      o[0] = (__bf16)a.x; o[1] = (__bf16)a.y; o[2] = (__bf16)a.z; o[3] = (__bf16)a.w;
      o[4] = (__bf16)b.x; o[5] = (__bf16)b.y; o[6] = (__bf16)b.z; o[7] = (__bf16)b.w;
      *reinterpret_cast<bf16x8*>(ktb + c * 8) = o;
    }
  }

  const float* __restrict__ vh = v + (size_t)head * (T_DIM * D_DIM);
  const float* __restrict__ afh = out_ro + OUT_AF + (size_t)head * (D_DIM * D_DIM);

#pragma unroll
  for (int i = 0; i < 16; ++i) {       // AF[d][e] fp32 -> aft[e][d] bf16 (transpose)
    int flat = i * 256 + tid;          // 0..4095
    int d = flat >> 5;
    int e4 = (flat & 31) << 2;
    float4 vv = *reinterpret_cast<const float4*>(afh + (size_t)d * D_DIM + e4);
    aft[swz(e4 + 0, d)] = (__bf16)vv.x;
    aft[swz(e4 + 1, d)] = (__bf16)vv.y;
    aft[swz(e4 + 2, d)] = (__bf16)vv.z;
    aft[swz(e4 + 3, d)] = (__bf16)vv.w;
  }
  stage_f32_tile_128(vh + (size_t)t0 * D_DIM, vt, tid, 1.0f);
  __syncthreads();

  f32x4 acc[2][8];
#pragma unroll
  for (int mt = 0; mt < 2; ++mt)
#pragma unroll
    for (int nt = 0; nt < 8; ++nt) acc[mt][nt] = (f32x4){0.f, 0.f, 0.f, 0.f};

#pragma unroll
  for (int ki = 0; ki < 4; ++ki) {
    bf16x8 a0 = ld8(vt, w * 32 + l16, ki * 32 + quad * 8);
    bf16x8 a1 = ld8(vt, w * 32 + 16 + l16, ki * 32 + quad * 8);
#pragma unroll
    for (int nt = 0; nt < 8; ++nt) {
      bf16x8 b = ld8(aft, nt * 16 + l16, ki * 32 + quad * 8);
      acc[0][nt] = MFMA16(a0, b, acc[0][nt], 0, 0, 0);
      acc[1][nt] = MFMA16(a1, b, acc[1][nt], 0, 0, 0);
    }
  }

  // Bounce acc -> LDS (WT tile layout [e][t_in_tile], swizzled), then emit
  // coalesced 16B global stores.
  __syncthreads();   // everyone done reading vt/aft
#pragma unroll
  for (int mt = 0; mt < 2; ++mt)
#pragma unroll
    for (int nt = 0; nt < 8; ++nt)
#pragma unroll
      for (int r = 0; r < 4; ++r)
        aft[swz(nt * 16 + l16, w * 32 + mt * 16 + quad * 4 + r)] = (__bf16)acc[mt][nt][r];
  __syncthreads();

  __bf16* __restrict__ wth = wt + (size_t)head * (D_DIM * T_DIM);
#pragma unroll
  for (int i = 0; i < 8; ++i) {
    int row = i * 16 + (tid >> 4);         // e
    int pc = tid & 15;
    bf16x8 vv = *reinterpret_cast<const bf16x8*>(&aft[(row << 7) + (pc << 3)]);
    int col = ((pc ^ row) & 15) << 3;      // t within tile
    *reinterpret_cast<bf16x8*>(&wth[(size_t)row * T_DIM + t0 + col]) = vv;
  }
}

// ---------------------------------------------------------------------------
// K12 v3: QBLK=256, 8 waves (512 thr), 96 KiB LDS in 3 x 32 KiB slabs.
// Each staged K/W tile now serves 256 output rows (2x the old 128) ->
// chip-wide K/W read traffic halves. Per-wave register layout unchanged
// (32 rows/wave). grid 256 = 4 row-tiles x 64 heads (same-head blocks still
// share an XCD: 64 % 8 == 0). Sweep1: depth-2 prefetch over 3 slabs.
// Sweep2: K->S0, W->S1, P rows 0-127 -> S2, rows 128-255 -> S0 (K consumed);
// counted vmcnt (loads 8/thr, P-NT-stores 16/thr => vmcnt(16) retires loads).
// ---------------------------------------------------------------------------
__global__ __launch_bounds__(512, 2)
void cd_attn_time_v3(const __bf16* __restrict__ qtb, const __bf16* __restrict__ ktb,
                     const __bf16* __restrict__ wt, float* __restrict__ out) {
  __shared__ __align__(16) __bf16 lds_all[3 * 16384];   // 96 KiB
  __bf16* S0 = lds_all;
  __bf16* S1 = lds_all + 16384;
  __bf16* S2 = lds_all + 32768;
  const int tid = threadIdx.x;
  const int w = tid >> 6;          // 0..7
  const int lane = tid & 63;
  const int quad = lane >> 4;
  const int l16 = lane & 15;
  const int head = blockIdx.x & 63;
  const int t0 = (blockIdx.x >> 6) << 8;   // 256-row tiles

  const __bf16* __restrict__ qth = qtb + (size_t)head * (T_DIM * D_DIM);
  const __bf16* __restrict__ kth = ktb + (size_t)head * (T_DIM * D_DIM);
  const __bf16* __restrict__ wth = wt + (size_t)head * (D_DIM * T_DIM);
  float* __restrict__ attn_out = out + OUT_ATTN + (size_t)head * ((size_t)T_DIM * T_DIM);
  float* __restrict__ o_out = out + (size_t)head * (T_DIM * D_DIM);

  // Prologue: K0->S0, K1->S1 async; A-fragments of (Qt/TEMP) from global.
  stage_async_tile512(kth, D_DIM, S0, tid);
  stage_async_tile512(kth + (size_t)128 * D_DIM, D_DIM, S1, tid);
  bf16x8 afrag[4][2];
#pragma unroll
  for (int ki = 0; ki < 4; ++ki) {
#pragma unroll
    for (int mt = 0; mt < 2; ++mt)
      afrag[ki][mt] = *reinterpret_cast<const bf16x8*>(
          qth + (size_t)(t0 + w * 32 + mt * 16 + l16) * D_DIM + ki * 32 + quad * 8);
  }

  // ---- sweep 1: row sums of exp(S); depth-2 K prefetch over 3 slabs ----
  float rs[2][4] = {{0.f, 0.f, 0.f, 0.f}, {0.f, 0.f, 0.f, 0.f}};
  for (int j = 0; j < 8; ++j) {
    if (j < 7)
      asm volatile("s_waitcnt vmcnt(4)" ::: "memory");   // K_j (+afrag at j=0) done
    else
      asm volatile("s_waitcnt vmcnt(0)" ::: "memory");
    __builtin_amdgcn_s_barrier();
    if (j < 6)
      stage_async_tile512(kth + (size_t)(j + 2) * (128 * D_DIM), D_DIM,
                          lds_all + ((j + 2) % 3) * 16384, tid);
    f32x4 sacc[2][8];
    compute_S(afrag, lds_all + (j % 3) * 16384, l16, quad, sacc);
#pragma unroll
    for (int mt = 0; mt < 2; ++mt)
#pragma unroll
      for (int nt = 0; nt < 8; ++nt)
#pragma unroll
        for (int r = 0; r < 4; ++r)
          rs[mt][r] += __expf(sacc[mt][nt][r]);
    asm volatile("s_waitcnt lgkmcnt(0)" ::: "memory");    // S reads done
    __builtin_amdgcn_s_barrier();                         // slab (j%3) now free
  }
#pragma unroll
  for (int off = 1; off < 16; off <<= 1)
#pragma unroll
    for (int mt = 0; mt < 2; ++mt)
#pragma unroll
      for (int r = 0; r < 4; ++r)
        rs[mt][r] += __shfl_xor(rs[mt][r], off, 64);
  float invl[2][4];
#pragma unroll
  for (int mt = 0; mt < 2; ++mt)
#pragma unroll
    for (int r = 0; r < 4; ++r)
      invl[mt][r] = 1.0f / rs[mt][r];

  // ---- sweep 2: S -> P (normalized) -> attn_time (NT) + O += P @ W ----
  f32x4 uacc[2][8];
#pragma unroll
  for (int mt = 0; mt < 2; ++mt)
#pragma unroll
    for (int nt = 0; nt < 8; ++nt) uacc[mt][nt] = (f32x4){0.f, 0.f, 0.f, 0.f};

  // Per-wave P slab: waves 0-3 -> S2 (P rows 0-127), waves 4-7 -> S0 (rows 128-255,
  // overwriting the consumed K tile).
  __bf16* pslab = (w < 4) ? S2 : S0;
  const int prow0 = (w & 3) * 32;

  stage_async_tile512(kth, D_DIM, S0, tid);
  stage_async_tile512(wth, T_DIM, S1, tid);
  for (int j = 0; j < 8; ++j) {
    if (j == 0)
      asm volatile("s_waitcnt vmcnt(0)" ::: "memory");    // K_0, W_0 landed
    else
      asm volatile("s_waitcnt vmcnt(16)" ::: "memory");   // retire exactly K_j, W_j;
                                                          // prev NT stores keep draining
    __builtin_amdgcn_s_barrier();
    f32x4 sacc[2][8];
    compute_S(afrag, S0, l16, quad, sacc);
    asm volatile("s_waitcnt lgkmcnt(0)" ::: "memory");    // all waves' K reads done
    __builtin_amdgcn_s_barrier();
    // P write (each wave its own 32 rows, into its slab)
#pragma unroll
    for (int mt = 0; mt < 2; ++mt)
#pragma unroll
      for (int nt = 0; nt < 8; ++nt)
#pragma unroll
        for (int r = 0; r < 4; ++r)
          pslab[swz(prow0 + mt * 16 + quad * 4 + r, nt * 16 + l16)] =
              (__bf16)(__expf(sacc[mt][nt][r]) * invl[mt][r]);
    asm volatile("s_waitcnt lgkmcnt(0)" ::: "memory");    // own P rows readable
    // O += P(own rows) @ W(S1)
#pragma unroll
    for (int ki = 0; ki < 4; ++ki) {
      bf16x8 aP0 = ld8(pslab, prow0 + l16, ki * 32 + quad * 8);
      bf16x8 aP1 = ld8(pslab, prow0 + 16 + l16, ki * 32 + quad * 8);
#pragma unroll
      for (int nt = 0; nt < 8; ++nt) {
        bf16x8 bW = ld8(S1, nt * 16 + l16, ki * 32 + quad * 8);
        uacc[0][nt] = MFMA16(aP0, bW, uacc[0][nt], 0, 0, 0);
        uacc[1][nt] = MFMA16(aP1, bW, uacc[1][nt], 0, 0, 0);
      }
    }
    asm volatile("s_waitcnt lgkmcnt(0)" ::: "memory");    // PV reads done
    __builtin_amdgcn_s_barrier();                         // all P writes visible
    // Pull full P tile (256 rows) into regs for the coalesced store.
    bf16x8 pv[8];
    const int pc = tid & 15;
#pragma unroll
    for (int i = 0; i < 8; ++i) {
      int row = i * 32 + (tid >> 4);                      // 0..255
      const __bf16* pb = (row < 128) ? S2 : S0;
      pv[i] = *reinterpret_cast<const bf16x8*>(&pb[((row & 127) << 7) + (pc << 3)]);
    }
    asm volatile("s_waitcnt lgkmcnt(0)" ::: "memory");    // pulls in regs
    __builtin_amdgcn_s_barrier();                         // S0/S1 free for next DMA
    if (j < 7) {
      stage_async_tile512(kth + (size_t)(j + 1) * (128 * D_DIM), D_DIM, S0, tid);
      stage_async_tile512(wth + (size_t)(j + 1) * 128, T_DIM, S1, tid);
    }
    asm volatile("" ::: "memory");
    __builtin_amdgcn_sched_barrier(0);                    // keep loads before stores
    // NT fp32 store of the P tile (logical col recovered from swizzle).
    const int s0 = j * 128;
#pragma unroll
    for (int i = 0; i < 8; ++i) {
      int row = i * 32 + (tid >> 4);
      int col = ((pc ^ row) & 15) << 3;
      float* dst = attn_out + (size_t)(t0 + row) * T_DIM + s0 + col;
      nt_store4(dst, (float)pv[i][0], (float)pv[i][1], (float)pv[i][2], (float)pv[i][3]);
      nt_store4(dst + 4, (float)pv[i][4], (float)pv[i][5], (float)pv[i][6], (float)pv[i][7]);
    }
  }

  // ---- O epilogue: two 128-row halves bounced through LDS (64 KiB each) ----
  float* fbuf = reinterpret_cast<float*>(lds_all);
#pragma unroll
  for (int h = 0; h < 2; ++h) {
    if ((w >> 2) == h) {
#pragma unroll
      for (int mt = 0; mt < 2; ++mt)
#pragma unroll
        for (int nt = 0; nt < 8; ++nt)
#pragma unroll
          for (int r = 0; r < 4; ++r)
            fbuf[((w & 3) * 32 + mt * 16 + quad * 4 + r) * 128 + nt * 16 + l16] =
                uacc[mt][nt][r];
    }
    asm volatile("s_waitcnt lgkmcnt(0)" ::: "memory");
    __builtin_amdgcn_s_barrier();
#pragma unroll
    for (int i = 0; i < 8; ++i) {
      int flat = i * 512 + tid;          // 0..4095 float4s = 128 rows x 32
      int row = flat >> 5;
      int c4 = (flat & 31) << 2;
      f32x4 vv = *reinterpret_cast<const f32x4*>(&fbuf[row * 128 + c4]);
      __builtin_nontemporal_store(
          vv, reinterpret_cast<f32x4*>(o_out + (size_t)(t0 + h * 128 + row) * D_DIM + c4));
    }
    asm volatile("s_waitcnt lgkmcnt(0)" ::: "memory");
    __builtin_amdgcn_s_barrier();                         // fbuf free for next half
  }
}

// ---------------------------------------------------------------------------
// Fallback K12 (proven baseline): fp32 reg staging, two sweeps, sync barriers.
// ---------------------------------------------------------------------------
__global__ __launch_bounds__(256, 2)
void cd_attn_time(const float* __restrict__ qt, const float* __restrict__ kt,
                  const __bf16* __restrict__ wt, float* __restrict__ out) {
  __shared__ __bf16 bufB[128 * 128];
  __shared__ __bf16 bufP[128 * 128];
  const int tid = threadIdx.x;
  const int w = tid >> 6;
  const int lane = tid & 63;
  const int quad = lane >> 4;
  const int l16 = lane & 15;
  const int head = blockIdx.x & 63;
  const int t0 = (blockIdx.x >> 6) << 7;

  const float* __restrict__ qth = qt + (size_t)head * (T_DIM * D_DIM);
  const float* __restrict__ kth = kt + (size_t)head * (T_DIM * D_DIM);
  const __bf16* __restrict__ wth = wt + (size_t)head * (D_DIM * T_DIM);
  float* __restrict__ attn_out = out + OUT_ATTN + (size_t)head * ((size_t)T_DIM * T_DIM);
  float* __restrict__ o_out = out + (size_t)head * (T_DIM * D_DIM);

  stage_f32_tile_128(qth + (size_t)t0 * D_DIM, bufB, tid, INV_TEMP);
  __syncthreads();
  bf16x8 afrag[4][2];
#pragma unroll
  for (int ki = 0; ki < 4; ++ki) {
    afrag[ki][0] = ld8(bufB, w * 32 + l16, ki * 32 + quad * 8);
    afrag[ki][1] = ld8(bufB, w * 32 + 16 + l16, ki * 32 + quad * 8);
  }

  float rs[2][4] = {{0.f, 0.f, 0.f, 0.f}, {0.f, 0.f, 0.f, 0.f}};
  for (int j = 0; j < 8; ++j) {
    __syncthreads();
    stage_f32_tile_128(kth + (size_t)(j * 128) * D_DIM, bufB, tid, 1.0f);
    __syncthreads();
    f32x4 sacc[2][8];
    compute_S(afrag, bufB, l16, quad, sacc);
#pragma unroll
    for (int mt = 0; mt < 2; ++mt)
#pragma unroll
      for (int nt = 0; nt < 8; ++nt)
#pragma unroll
        for (int r = 0; r < 4; ++r)
          rs[mt][r] += __expf(sacc[mt][nt][r]);
  }
#pragma unroll
  for (int off = 1; off < 16; off <<= 1)
#pragma unroll
    for (int mt = 0; mt < 2; ++mt)
#pragma unroll
      for (int r = 0; r < 4; ++r)
        rs[mt][r] += __shfl_xor(rs[mt][r], off, 64);
  float invl[2][4];
#pragma unroll
  for (int mt = 0; mt < 2; ++mt)
#pragma unroll
    for (int r = 0; r < 4; ++r)
      invl[mt][r] = 1.0f / rs[mt][r];

  f32x4 uacc[2][8];
#pragma unroll
  for (int mt = 0; mt < 2; ++mt)
#pragma unroll
    for (int nt = 0; nt < 8; ++nt) uacc[mt][nt] = (f32x4){0.f, 0.f, 0.f, 0.f};

  for (int j = 0; j < 8; ++j) {
    __syncthreads();
    stage_f32_tile_128(kth + (size_t)(j * 128) * D_DIM, bufB, tid, 1.0f);
    __syncthreads();
    f32x4 sacc[2][8];
    compute_S(afrag, bufB, l16, quad, sacc);
    __syncthreads();
    stage_wt_tile(wth + j * 128, bufB, tid);
#pragma unroll
    for (int mt = 0; mt < 2; ++mt)
#pragma unroll
      for (int nt = 0; nt < 8; ++nt)
#pragma unroll
        for (int r = 0; r < 4; ++r) {
          float p = __expf(sacc[mt][nt][r]) * invl[mt][r];
          bufP[swz(w * 32 + mt * 16 + quad * 4 + r, nt * 16 + l16)] = (__bf16)p;
        }
    __syncthreads();
    const int s0 = j * 128;
#pragma unroll
    for (int i = 0; i < 8; ++i) {
      int row = i * 16 + (tid >> 4);
      int pc = tid & 15;
      bf16x8 pv = *reinterpret_cast<const bf16x8*>(&bufP[(row << 7) + (pc << 3)]);
      int col = ((pc ^ row) & 15) << 3;
      float4 o1, o2;
      o1.x = (float)pv[0]; o1.y = (float)pv[1]; o1.z = (float)pv[2]; o1.w = (float)pv[3];
      o2.x = (float)pv[4]; o2.y = (float)pv[5]; o2.z = (float)pv[6]; o2.w = (float)pv[7];
      float4* dstp = reinterpret_cast<float4*>(attn_out + (size_t)(t0 + row) * T_DIM + s0 + col);
      dstp[0] = o1;
      dstp[1] = o2;
    }
#pragma unroll
    for (int ki = 0; ki < 4; ++ki) {
      bf16x8 aP0 = ld8(bufP, w * 32 + l16, ki * 32 + quad * 8);
      bf16x8 aP1 = ld8(bufP, w * 32 + 16 + l16, ki * 32 + quad * 8);
#pragma unroll
      for (int nt = 0; nt < 8; ++nt) {
        bf16x8 bW = ld8(bufB, nt * 16 + l16, ki * 32 + quad * 8);
        uacc[0][nt] = MFMA16(aP0, bW, uacc[0][nt], 0, 0, 0);
        uacc[1][nt] = MFMA16(aP1, bW, uacc[1][nt], 0, 0, 0);
      }
    }
  }

#pragma unroll
  for (int mt = 0; mt < 2; ++mt)
#pragma unroll
    for (int nt = 0; nt < 8; ++nt)
#pragma unroll
      for (int r = 0; r < 4; ++r)
        o_out[(size_t)(t0 + w * 32 + mt * 16 + quad * 4 + r) * D_DIM + nt * 16 + l16] =
            uacc[mt][nt][r];
}

extern "C" void kernel_launch(void* const* d_in, const int* in_sizes, int n_in,
                              void* d_out, int out_size, void* d_ws, size_t ws_size,
                              hipStream_t stream) {
  (void)in_sizes; (void)n_in; (void)out_size;
  const float* q_time    = (const float*)d_in[0];
  const float* k_time    = (const float*)d_in[1];
  const float* q_feature = (const float*)d_in[2];
  const float* k_feature = (const float*)d_in[3];
  const float* v         = (const float*)d_in[4];
  float* out = (float*)d_out;
  __bf16* wt = (__bf16*)d_ws;                         // WT[64][128][1024] bf16 = 16 MiB

  const size_t NELEM = (size_t)NHEAD * T_DIM * D_DIM; // 8388608
  const size_t WS_NEED = NELEM * 2 * 3;               // WT + qtb + ktb (48 MiB)

  if (ws_size >= WS_NEED) {
    __bf16* qtb = wt + NELEM;
    __bf16* ktb = qtb + NELEM;
    cd_attn_feature<<<128, 256, 0, stream>>>(q_feature, k_feature, out);
    cd_attn_w<<<512, 256, 0, stream>>>(v, out, wt, q_time, k_time, qtb, ktb);
    cd_attn_time_v3<<<256, 512, 0, stream>>>(qtb, ktb, wt, out);
  } else {
    cd_attn_feature<<<128, 256, 0, stream>>>(q_feature, k_feature, out);
    cd_attn_w<<<512, 256, 0, stream>>>(v, out, wt, nullptr, nullptr, nullptr, nullptr);
    cd_attn_time<<<512, 256, 0, stream>>>(q_time, k_time, wt, out);
  }
}

// Round 6
// 617.262 us; speedup vs baseline: 1.1544x; 1.1544x over previous
//
#include <hip/hip_runtime.h>

typedef __bf16 bf16x8 __attribute__((ext_vector_type(8)));
typedef __bf16 bf16x4 __attribute__((ext_vector_type(4)));
typedef float f32x4 __attribute__((ext_vector_type(4)));

#define T_DIM 1024
#define D_DIM 128
#define NHEAD 64

static constexpr float INV_TEMP = 0.08838834764831845f; // 1/sqrt(128)
static constexpr size_t OUT_ATTN = (size_t)NHEAD * T_DIM * D_DIM;            // 8388608
static constexpr size_t OUT_AF = OUT_ATTN + (size_t)NHEAD * T_DIM * T_DIM;   // 75497472

#define MFMA16 __builtin_amdgcn_mfma_f32_16x16x32_bf16

// XOR-swizzled pitch-128 LDS layout: 8-element chunks permuted by row to avoid
// bank conflicts without padding (keeps 2 buffers in exactly 64 KiB).
__device__ __forceinline__ int swz(int row, int col) {
  return (row << 7) + ((((col >> 3) ^ row) & 15) << 3) + (col & 7);
}

__device__ __forceinline__ bf16x8 ld8(const __bf16* buf, int row, int col) {
  return *reinterpret_cast<const bf16x8*>(&buf[swz(row, col)]);
}

// NT store helper using a clang ext_vector (HIP float4 is a class and is
// rejected by __builtin_nontemporal_store).
__device__ __forceinline__ void nt_store4(float* dst, float a, float b, float c, float d) {
  f32x4 v = {a, b, c, d};
  __builtin_nontemporal_store(v, reinterpret_cast<f32x4*>(dst));
}

// Stage a contiguous 128x128 fp32 tile (row stride 128 floats) into swizzled bf16 LDS.
__device__ __forceinline__ void stage_f32_tile_128(const float* __restrict__ src,
                                                   __bf16* dst, int tid, float scale) {
  const float4* s4 = reinterpret_cast<const float4*>(src);
#pragma unroll
  for (int i = 0; i < 16; ++i) {
    int flat = i * 256 + tid;   // 0..4095 float4s
    int row = flat >> 5;
    int c4 = (flat & 31) << 2;
    float4 vq = s4[flat];
    bf16x4 b;
    b[0] = (__bf16)(vq.x * scale);
    b[1] = (__bf16)(vq.y * scale);
    b[2] = (__bf16)(vq.z * scale);
    b[3] = (__bf16)(vq.w * scale);
    *reinterpret_cast<bf16x4*>(&dst[swz(row, c4)]) = b;
  }
}

// Stage a 128x128 bf16 tile from WT (row stride T_DIM) into swizzled LDS (reg path,
// fallback kernel only).
__device__ __forceinline__ void stage_wt_tile(const __bf16* __restrict__ src,
                                              __bf16* dst, int tid) {
#pragma unroll
  for (int i = 0; i < 8; ++i) {
    int flat = i * 256 + tid;   // 0..2047 chunks of 8
    int row = flat >> 4;
    int c8 = (flat & 15) << 3;
    bf16x8 vv = *reinterpret_cast<const bf16x8*>(src + (size_t)row * T_DIM + c8);
    *reinterpret_cast<bf16x8*>(&dst[swz(row, c8)]) = vv;
  }
}

// ---- async (global_load_lds) staging: LDS written linearly by the DMA, the
// XOR swizzle is applied on the per-lane *source* address (m173 pattern), so
// ld8()/swz() readers are unchanged. 8 instructions per wave per 32 KiB tile.
__device__ __forceinline__ void cp16_async(const void* g, void* l) {
  typedef __attribute__((address_space(1))) unsigned int gu32;
  typedef __attribute__((address_space(3))) unsigned int lu32;
  __builtin_amdgcn_global_load_lds((gu32*)g, (lu32*)l, 16, 0, 0);
}

__device__ __forceinline__ void stage_async_tile(const __bf16* __restrict__ gbase,
                                                 int row_stride_elems,
                                                 __bf16* lbuf, int tid) {
  const int w = tid >> 6;
  const int lane = tid & 63;
#pragma unroll
  for (int i = 0; i < 8; ++i) {
    int seg = i * 4 + w;                 // 32 segments of 1 KiB
    int row = seg * 4 + (lane >> 4);     // 0..127
    int c = ((lane & 15) ^ row) & 15;    // pre-swizzled source chunk
    const void* src = (const void*)(gbase + (size_t)row * row_stride_elems + c * 8);
    void* dst = (void*)(lbuf + seg * 512);   // wave-uniform LDS base
    cp16_async(src, dst);
  }
}

// S = A(regs) * B(LDS): per-wave 32x128 tile, K=128.
__device__ __forceinline__ void compute_S(const bf16x8 afrag[4][2], const __bf16* bufB,
                                          int l16, int quad, f32x4 sacc[2][8]) {
#pragma unroll
  for (int mt = 0; mt < 2; ++mt)
#pragma unroll
    for (int nt = 0; nt < 8; ++nt)
      sacc[mt][nt] = (f32x4){0.f, 0.f, 0.f, 0.f};
#pragma unroll
  for (int ki = 0; ki < 4; ++ki) {
    bf16x8 bfr[8];
#pragma unroll
    for (int nt = 0; nt < 8; ++nt)
      bfr[nt] = ld8(bufB, nt * 16 + l16, ki * 32 + quad * 8);
#pragma unroll
    for (int nt = 0; nt < 8; ++nt) {
      sacc[0][nt] = MFMA16(afrag[ki][0], bfr[nt], sacc[0][nt], 0, 0, 0);
      sacc[1][nt] = MFMA16(afrag[ki][1], bfr[nt], sacc[1][nt], 0, 0, 0);
    }
  }
}

// ---------------------------------------------------------------------------
// KF + prep (heterogeneous grid):
//   blocks 0..127   : attn_feature (softmax over e of qf^T kf / TEMP)
//   blocks 128..383 : qtb = bf16(qt*INV_TEMP), ktb = bf16(kt)  (fills the half
//                     of the chip feature leaves idle; removes prep from KW)
// Feature staging is register-double-buffered: chunk t+32 global loads are
// issued under chunk t's MFMA, hiding HBM latency (was fully serial).
// ---------------------------------------------------------------------------
__global__ __launch_bounds__(256, 2)
void cd_attn_feature(const float* __restrict__ qf, const float* __restrict__ kf,
                     float* __restrict__ out,
                     const float* __restrict__ qt, const float* __restrict__ kt,
                     __bf16* __restrict__ qtb, __bf16* __restrict__ ktb) {
  const int tid = threadIdx.x;

  if (blockIdx.x >= 128) {              // ---- prep blocks ----
    const int pbid = blockIdx.x - 128;  // 0..255
    const float4* q4 = reinterpret_cast<const float4*>(qt);
    const float4* k4 = reinterpret_cast<const float4*>(kt);
    size_t base = (size_t)pbid * 4096 + tid;   // 256*4096*8 = 8388608 elems
#pragma unroll
    for (int i = 0; i < 16; ++i) {
      size_t c = base + (size_t)(i * 256);
      float4 a = q4[c * 2], b = q4[c * 2 + 1];
      bf16x8 o;
      o[0] = (__bf16)(a.x * INV_TEMP); o[1] = (__bf16)(a.y * INV_TEMP);
      o[2] = (__bf16)(a.z * INV_TEMP); o[3] = (__bf16)(a.w * INV_TEMP);
      o[4] = (__bf16)(b.x * INV_TEMP); o[5] = (__bf16)(b.y * INV_TEMP);
      o[6] = (__bf16)(b.z * INV_TEMP); o[7] = (__bf16)(b.w * INV_TEMP);
      *reinterpret_cast<bf16x8*>(qtb + c * 8) = o;
      a = k4[c * 2]; b = k4[c * 2 + 1];
      o[0] = (__bf16)a.x; o[1] = (__bf16)a.y; o[2] = (__bf16)a.z; o[3] = (__bf16)a.w;
      o[4] = (__bf16)b.x; o[5] = (__bf16)b.y; o[6] = (__bf16)b.z; o[7] = (__bf16)b.w;
      *reinterpret_cast<bf16x8*>(ktb + c * 8) = o;
    }
    return;
  }

  // ---- feature blocks ----
  __shared__ __bf16 qfT[64][40];    // [d][t] pitch 40 (80B rows, 16B aligned)
  __shared__ __bf16 kfT[128][40];   // [e][t]
  const int w = tid >> 6;
  const int lane = tid & 63;
  const int quad = lane >> 4;
  const int l16 = lane & 15;
  const int head = blockIdx.x & 63;
  const int dstart = (blockIdx.x >> 6) << 6;

  const float* __restrict__ qfh = qf + (size_t)head * (T_DIM * D_DIM);
  const float* __restrict__ kfh = kf + (size_t)head * (T_DIM * D_DIM);

  f32x4 acc[8];
#pragma unroll
  for (int nt = 0; nt < 8; ++nt) acc[nt] = (f32x4){0.f, 0.f, 0.f, 0.f};

  // Per-thread source coords (fixed across chunks).
  const int qt_ = tid >> 4, qd4 = (tid & 15) << 2;            // i<2 loop folded
  const int kt_ = tid >> 5, ke4 = (tid & 31) << 2;            // i<4 loop folded

  float4 qreg[2], kreg[4];
#pragma unroll
  for (int i = 0; i < 2; ++i)
    qreg[i] = *reinterpret_cast<const float4*>(
        qfh + (size_t)(i * 16 + qt_) * D_DIM + dstart + qd4);
#pragma unroll
  for (int i = 0; i < 4; ++i)
    kreg[i] = *reinterpret_cast<const float4*>(
        kfh + (size_t)(i * 8 + kt_) * D_DIM + ke4);

  for (int tc = 0; tc < T_DIM; tc += 32) {
    __syncthreads();                    // previous chunk's readers done
#pragma unroll
    for (int i = 0; i < 2; ++i) {       // qf chunk regs -> qfT (transpose)
      int t = i * 16 + qt_;
      qfT[qd4 + 0][t] = (__bf16)qreg[i].x;
      qfT[qd4 + 1][t] = (__bf16)qreg[i].y;
      qfT[qd4 + 2][t] = (__bf16)qreg[i].z;
      qfT[qd4 + 3][t] = (__bf16)qreg[i].w;
    }
#pragma unroll
    for (int i = 0; i < 4; ++i) {       // kf chunk regs -> kfT (transpose)
      int t = i * 8 + kt_;
      kfT[ke4 + 0][t] = (__bf16)kreg[i].x;
      kfT[ke4 + 1][t] = (__bf16)kreg[i].y;
      kfT[ke4 + 2][t] = (__bf16)kreg[i].z;
      kfT[ke4 + 3][t] = (__bf16)kreg[i].w;
    }
    if (tc + 32 < T_DIM) {              // prefetch next chunk (hidden under MFMA)
#pragma unroll
      for (int i = 0; i < 2; ++i)
        qreg[i] = *reinterpret_cast<const float4*>(
            qfh + (size_t)(tc + 32 + i * 16 + qt_) * D_DIM + dstart + qd4);
#pragma unroll
      for (int i = 0; i < 4; ++i)
        kreg[i] = *reinterpret_cast<const float4*>(
            kfh + (size_t)(tc + 32 + i * 8 + kt_) * D_DIM + ke4);
    }
    __syncthreads();
    bf16x8 a = *reinterpret_cast<const bf16x8*>(&qfT[w * 16 + l16][quad * 8]);
#pragma unroll
    for (int nt = 0; nt < 8; ++nt) {
      bf16x8 b = *reinterpret_cast<const bf16x8*>(&kfT[nt * 16 + l16][quad * 8]);
      acc[nt] = MFMA16(a, b, acc[nt], 0, 0, 0);
    }
  }

  float p[8][4];
  float rsum[4] = {0.f, 0.f, 0.f, 0.f};
#pragma unroll
  for (int nt = 0; nt < 8; ++nt)
#pragma unroll
    for (int r = 0; r < 4; ++r) {
      p[nt][r] = __expf(acc[nt][r] * INV_TEMP);
      rsum[r] += p[nt][r];
    }
#pragma unroll
  for (int off = 1; off < 16; off <<= 1)
#pragma unroll
    for (int r = 0; r < 4; ++r)
      rsum[r] += __shfl_xor(rsum[r], off, 64);
#pragma unroll
  for (int r = 0; r < 4; ++r) rsum[r] = 1.0f / rsum[r];

  float* __restrict__ afh = out + OUT_AF + (size_t)head * (D_DIM * D_DIM);
#pragma unroll
  for (int nt = 0; nt < 8; ++nt)
#pragma unroll
    for (int r = 0; r < 4; ++r)
      afh[(size_t)(dstart + w * 16 + quad * 4 + r) * D_DIM + nt * 16 + l16] = p[nt][r] * rsum[r];
}

// ---------------------------------------------------------------------------
// KW: W = V @ AF per head; store transposed WT[head][e][t] in bf16 (d_ws).
// grid 512 = 8 row-tiles x 64 heads. (prep moved to the feature launch)
// ---------------------------------------------------------------------------
__global__ __launch_bounds__(256, 2)
void cd_attn_w(const float* __restrict__ v, const float* __restrict__ out_ro,
               __bf16* __restrict__ wt) {
  __shared__ __bf16 vt[128 * 128];
  __shared__ __bf16 aft[128 * 128];   // aft[e][d]; reused as WT-tile bounce
  const int tid = threadIdx.x;
  const int w = tid >> 6;
  const int lane = tid & 63;
  const int quad = lane >> 4;
  const int l16 = lane & 15;
  const int head = blockIdx.x & 63;
  const int t0 = (blockIdx.x >> 6) << 7;

  const float* __restrict__ vh = v + (size_t)head * (T_DIM * D_DIM);
  const float* __restrict__ afh = out_ro + OUT_AF + (size_t)head * (D_DIM * D_DIM);

#pragma unroll
  for (int i = 0; i < 16; ++i) {       // AF[d][e] fp32 -> aft[e][d] bf16 (transpose)
    int flat = i * 256 + tid;          // 0..4095
    int d = flat >> 5;
    int e4 = (flat & 31) << 2;
    float4 vv = *reinterpret_cast<const float4*>(afh + (size_t)d * D_DIM + e4);
    aft[swz(e4 + 0, d)] = (__bf16)vv.x;
    aft[swz(e4 + 1, d)] = (__bf16)vv.y;
    aft[swz(e4 + 2, d)] = (__bf16)vv.z;
    aft[swz(e4 + 3, d)] = (__bf16)vv.w;
  }
  stage_f32_tile_128(vh + (size_t)t0 * D_DIM, vt, tid, 1.0f);
  __syncthreads();

  f32x4 acc[2][8];
#pragma unroll
  for (int mt = 0; mt < 2; ++mt)
#pragma unroll
    for (int nt = 0; nt < 8; ++nt) acc[mt][nt] = (f32x4){0.f, 0.f, 0.f, 0.f};

#pragma unroll
  for (int ki = 0; ki < 4; ++ki) {
    bf16x8 a0 = ld8(vt, w * 32 + l16, ki * 32 + quad * 8);
    bf16x8 a1 = ld8(vt, w * 32 + 16 + l16, ki * 32 + quad * 8);
#pragma unroll
    for (int nt = 0; nt < 8; ++nt) {
      bf16x8 b = ld8(aft, nt * 16 + l16, ki * 32 + quad * 8);
      acc[0][nt] = MFMA16(a0, b, acc[0][nt], 0, 0, 0);
      acc[1][nt] = MFMA16(a1, b, acc[1][nt], 0, 0, 0);
    }
  }

  // Bounce acc -> LDS (WT tile layout [e][t_in_tile], swizzled), then emit
  // coalesced 16B global stores.
  __syncthreads();   // everyone done reading vt/aft
#pragma unroll
  for (int mt = 0; mt < 2; ++mt)
#pragma unroll
    for (int nt = 0; nt < 8; ++nt)
#pragma unroll
      for (int r = 0; r < 4; ++r)
        aft[swz(nt * 16 + l16, w * 32 + mt * 16 + quad * 4 + r)] = (__bf16)acc[mt][nt][r];
  __syncthreads();

  __bf16* __restrict__ wth = wt + (size_t)head * (D_DIM * T_DIM);
#pragma unroll
  for (int i = 0; i < 8; ++i) {
    int row = i * 16 + (tid >> 4);         // e
    int pc = tid & 15;
    bf16x8 vv = *reinterpret_cast<const bf16x8*>(&aft[(row << 7) + (pc << 3)]);
    int col = ((pc ^ row) & 15) << 3;      // t within tile
    *reinterpret_cast<bf16x8*>(&wth[(size_t)row * T_DIM + t0 + col]) = vv;
  }
}

// ---------------------------------------------------------------------------
// K12 v2 (proven 219 us, round-4 exact): NT output stores, loads-before-stores
// vmcnt ordering, LDS-bounced O epilogue. 64 KiB LDS -> 2 blocks/CU.
// ---------------------------------------------------------------------------
__global__ __launch_bounds__(256, 2)
void cd_attn_time_v2(const __bf16* __restrict__ qtb, const __bf16* __restrict__ ktb,
                     const __bf16* __restrict__ wt, float* __restrict__ out) {
  __shared__ __align__(16) __bf16 lds_all[2 * 128 * 128];   // 64 KiB
  __bf16* buf0 = lds_all;
  __bf16* buf1 = lds_all + 128 * 128;
  const int tid = threadIdx.x;
  const int w = tid >> 6;
  const int lane = tid & 63;
  const int quad = lane >> 4;
  const int l16 = lane & 15;
  const int head = blockIdx.x & 63;
  const int t0 = (blockIdx.x >> 6) << 7;

  const __bf16* __restrict__ qth = qtb + (size_t)head * (T_DIM * D_DIM);
  const __bf16* __restrict__ kth = ktb + (size_t)head * (T_DIM * D_DIM);
  const __bf16* __restrict__ wth = wt + (size_t)head * (D_DIM * T_DIM);
  float* __restrict__ attn_out = out + OUT_ATTN + (size_t)head * ((size_t)T_DIM * T_DIM);
  float* __restrict__ o_out = out + (size_t)head * (T_DIM * D_DIM);

  // Prologue: async K_0 -> buf0; A-fragments of (Qt/TEMP) straight from global.
  stage_async_tile(kth, D_DIM, buf0, tid);
  bf16x8 afrag[4][2];
#pragma unroll
  for (int ki = 0; ki < 4; ++ki) {
#pragma unroll
    for (int mt = 0; mt < 2; ++mt)
      afrag[ki][mt] = *reinterpret_cast<const bf16x8*>(
          qth + (size_t)(t0 + w * 32 + mt * 16 + l16) * D_DIM + ki * 32 + quad * 8);
  }

  // ---- sweep 1: row sums of exp(S); K tiles double-buffered, 1 iter ahead ----
  float rs[2][4] = {{0.f, 0.f, 0.f, 0.f}, {0.f, 0.f, 0.f, 0.f}};
  for (int j = 0; j < 8; ++j) {
    if (j < 7) {
      stage_async_tile(kth + (size_t)(j + 1) * (128 * D_DIM), D_DIM,
                       (j & 1) ? buf0 : buf1, tid);
      asm volatile("s_waitcnt vmcnt(8)" ::: "memory");   // K_j landed, K_{j+1} flies
    } else {
      asm volatile("s_waitcnt vmcnt(0)" ::: "memory");
    }
    __builtin_amdgcn_s_barrier();
    f32x4 sacc[2][8];
    compute_S(afrag, (j & 1) ? buf1 : buf0, l16, quad, sacc);
#pragma unroll
    for (int mt = 0; mt < 2; ++mt)
#pragma unroll
      for (int nt = 0; nt < 8; ++nt)
#pragma unroll
        for (int r = 0; r < 4; ++r)
          rs[mt][r] += __expf(sacc[mt][nt][r]);
    asm volatile("s_waitcnt lgkmcnt(0)" ::: "memory");    // S reads done
    __builtin_amdgcn_s_barrier();                         // DMA may stay in flight
  }
#pragma unroll
  for (int off = 1; off < 16; off <<= 1)
#pragma unroll
    for (int mt = 0; mt < 2; ++mt)
#pragma unroll
      for (int r = 0; r < 4; ++r)
        rs[mt][r] += __shfl_xor(rs[mt][r], off, 64);
  float invl[2][4];
#pragma unroll
  for (int mt = 0; mt < 2; ++mt)
#pragma unroll
    for (int r = 0; r < 4; ++r)
      invl[mt][r] = 1.0f / rs[mt][r];

  // ---- sweep 2: S -> P (normalized) -> attn_time (NT) + O += P @ W ----
  f32x4 uacc[2][8];
#pragma unroll
  for (int mt = 0; mt < 2; ++mt)
#pragma unroll
    for (int nt = 0; nt < 8; ++nt) uacc[mt][nt] = (f32x4){0.f, 0.f, 0.f, 0.f};

  stage_async_tile(kth, D_DIM, buf0, tid);
  stage_async_tile(wth, T_DIM, buf1, tid);
  for (int j = 0; j < 8; ++j) {
    if (j == 0)
      asm volatile("s_waitcnt vmcnt(0)" ::: "memory");    // K_0, W_0 landed
    else
      asm volatile("s_waitcnt vmcnt(16)" ::: "memory");   // retire exactly K_j, W_j;
                                                          // prev NT stores keep draining
    __builtin_amdgcn_s_barrier();
    f32x4 sacc[2][8];
    compute_S(afrag, buf0, l16, quad, sacc);
    asm volatile("s_waitcnt lgkmcnt(0)" ::: "memory");    // all waves' S reads of buf0 done
    __builtin_amdgcn_s_barrier();
    // P overwrites buf0 (each wave writes only its own 32 rows)
#pragma unroll
    for (int mt = 0; mt < 2; ++mt)
#pragma unroll
      for (int nt = 0; nt < 8; ++nt)
#pragma unroll
        for (int r = 0; r < 4; ++r)
          buf0[swz(w * 32 + mt * 16 + quad * 4 + r, nt * 16 + l16)] =
              (__bf16)(__expf(sacc[mt][nt][r]) * invl[mt][r]);
    asm volatile("s_waitcnt lgkmcnt(0)" ::: "memory");    // own P rows readable
    // O += P(buf0, own rows) @ W(buf1) — no cross-wave dep on P here.
#pragma unroll
    for (int ki = 0; ki < 4; ++ki) {
      bf16x8 aP0 = ld8(buf0, w * 32 + l16, ki * 32 + quad * 8);
      bf16x8 aP1 = ld8(buf0, w * 32 + 16 + l16, ki * 32 + quad * 8);
#pragma unroll
      for (int nt = 0; nt < 8; ++nt) {
        bf16x8 bW = ld8(buf1, nt * 16 + l16, ki * 32 + quad * 8);
        uacc[0][nt] = MFMA16(aP0, bW, uacc[0][nt], 0, 0, 0);
        uacc[1][nt] = MFMA16(aP1, bW, uacc[1][nt], 0, 0, 0);
      }
    }
    asm volatile("s_waitcnt lgkmcnt(0)" ::: "memory");    // PV reads done
    __builtin_amdgcn_s_barrier();                         // all P writes visible
    // Pull full P tile (cross-wave rows) into regs for the store.
    bf16x8 pv[8];
#pragma unroll
    for (int i = 0; i < 8; ++i) {
      int row = i * 16 + (tid >> 4);
      int pc = tid & 15;
      pv[i] = *reinterpret_cast<const bf16x8*>(&buf0[(row << 7) + (pc << 3)]);
    }
    asm volatile("s_waitcnt lgkmcnt(0)" ::: "memory");    // P reads in regs
    __builtin_amdgcn_s_barrier();                         // bufs free for next DMA
    if (j < 7) {
      stage_async_tile(kth + (size_t)(j + 1) * (128 * D_DIM), D_DIM, buf0, tid);
      stage_async_tile(wth + (size_t)(j + 1) * 128, T_DIM, buf1, tid);
    }
    asm volatile("" ::: "memory");                        // keep loads before stores
    __builtin_amdgcn_sched_barrier(0);
    // NT fp32 store of the P tile (logical col recovered from swizzle).
    const int s0 = j * 128;
#pragma unroll
    for (int i = 0; i < 8; ++i) {
      int row = i * 16 + (tid >> 4);
      int pc = tid & 15;
      int col = ((pc ^ row) & 15) << 3;
      float* dst = attn_out + (size_t)(t0 + row) * T_DIM + s0 + col;
      nt_store4(dst, (float)pv[i][0], (float)pv[i][1], (float)pv[i][2], (float)pv[i][3]);
      nt_store4(dst + 4, (float)pv[i][4], (float)pv[i][5], (float)pv[i][6], (float)pv[i][7]);
    }
  }

  // ---- O epilogue: bounce through LDS (free now) for full-line NT stores ----
  float* fbuf = reinterpret_cast<float*>(lds_all);        // 128 x 128 fp32 = 64 KiB
#pragma unroll
  for (int mt = 0; mt < 2; ++mt)
#pragma unroll
    for (int nt = 0; nt < 8; ++nt)
#pragma unroll
      for (int r = 0; r < 4; ++r)
        fbuf[(w * 32 + mt * 16 + quad * 4 + r) * 128 + nt * 16 + l16] = uacc[mt][nt][r];
  asm volatile("s_waitcnt lgkmcnt(0)" ::: "memory");
  __builtin_amdgcn_s_barrier();
#pragma unroll
  for (int i = 0; i < 16; ++i) {       // 4096 float4s = 128 rows x 32 float4s
    int flat = i * 256 + tid;
    int row = flat >> 5;
    int c4 = (flat & 31) << 2;
    f32x4 vv = *reinterpret_cast<const f32x4*>(&fbuf[row * 128 + c4]);
    __builtin_nontemporal_store(
        vv, reinterpret_cast<f32x4*>(o_out + (size_t)(t0 + row) * D_DIM + c4));
  }
}

// ---------------------------------------------------------------------------
// Fallback K12 (proven baseline): fp32 reg staging, two sweeps, sync barriers.
// ---------------------------------------------------------------------------
__global__ __launch_bounds__(256, 2)
void cd_attn_time(const float* __restrict__ qt, const float* __restrict__ kt,
                  const __bf16* __restrict__ wt, float* __restrict__ out) {
  __shared__ __bf16 bufB[128 * 128];
  __shared__ __bf16 bufP[128 * 128];
  const int tid = threadIdx.x;
  const int w = tid >> 6;
  const int lane = tid & 63;
  const int quad = lane >> 4;
  const int l16 = lane & 15;
  const int head = blockIdx.x & 63;
  const int t0 = (blockIdx.x >> 6) << 7;

  const float* __restrict__ qth = qt + (size_t)head * (T_DIM * D_DIM);
  const float* __restrict__ kth = kt + (size_t)head * (T_DIM * D_DIM);
  const __bf16* __restrict__ wth = wt + (size_t)head * (D_DIM * T_DIM);
  float* __restrict__ attn_out = out + OUT_ATTN + (size_t)head * ((size_t)T_DIM * T_DIM);
  float* __restrict__ o_out = out + (size_t)head * (T_DIM * D_DIM);

  stage_f32_tile_128(qth + (size_t)t0 * D_DIM, bufB, tid, INV_TEMP);
  __syncthreads();
  bf16x8 afrag[4][2];
#pragma unroll
  for (int ki = 0; ki < 4; ++ki) {
    afrag[ki][0] = ld8(bufB, w * 32 + l16, ki * 32 + quad * 8);
    afrag[ki][1] = ld8(bufB, w * 32 + 16 + l16, ki * 32 + quad * 8);
  }

  float rs[2][4] = {{0.f, 0.f, 0.f, 0.f}, {0.f, 0.f, 0.f, 0.f}};
  for (int j = 0; j < 8; ++j) {
    __syncthreads();
    stage_f32_tile_128(kth + (size_t)(j * 128) * D_DIM, bufB, tid, 1.0f);
    __syncthreads();
    f32x4 sacc[2][8];
    compute_S(afrag, bufB, l16, quad, sacc);
#pragma unroll
    for (int mt = 0; mt < 2; ++mt)
#pragma unroll
      for (int nt = 0; nt < 8; ++nt)
#pragma unroll
        for (int r = 0; r < 4; ++r)
          rs[mt][r] += __expf(sacc[mt][nt][r]);
  }
#pragma unroll
  for (int off = 1; off < 16; off <<= 1)
#pragma unroll
    for (int mt = 0; mt < 2; ++mt)
#pragma unroll
      for (int r = 0; r < 4; ++r)
        rs[mt][r] += __shfl_xor(rs[mt][r], off, 64);
  float invl[2][4];
#pragma unroll
  for (int mt = 0; mt < 2; ++mt)
#pragma unroll
    for (int r = 0; r < 4; ++r)
      invl[mt][r] = 1.0f / rs[mt][r];

  f32x4 uacc[2][8];
#pragma unroll
  for (int mt = 0; mt < 2; ++mt)
#pragma unroll
    for (int nt = 0; nt < 8; ++nt) uacc[mt][nt] = (f32x4){0.f, 0.f, 0.f, 0.f};

  for (int j = 0; j < 8; ++j) {
    __syncthreads();
    stage_f32_tile_128(kth + (size_t)(j * 128) * D_DIM, bufB, tid, 1.0f);
    __syncthreads();
    f32x4 sacc[2][8];
    compute_S(afrag, bufB, l16, quad, sacc);
    __syncthreads();
    stage_wt_tile(wth + j * 128, bufB, tid);
#pragma unroll
    for (int mt = 0; mt < 2; ++mt)
#pragma unroll
      for (int nt = 0; nt < 8; ++nt)
#pragma unroll
        for (int r = 0; r < 4; ++r) {
          float p = __expf(sacc[mt][nt][r]) * invl[mt][r];
          bufP[swz(w * 32 + mt * 16 + quad * 4 + r, nt * 16 + l16)] = (__bf16)p;
        }
    __syncthreads();
    const int s0 = j * 128;
#pragma unroll
    for (int i = 0; i < 8; ++i) {
      int row = i * 16 + (tid >> 4);
      int pc = tid & 15;
      bf16x8 pv = *reinterpret_cast<const bf16x8*>(&bufP[(row << 7) + (pc << 3)]);
      int col = ((pc ^ row) & 15) << 3;
      float4 o1, o2;
      o1.x = (float)pv[0]; o1.y = (float)pv[1]; o1.z = (float)pv[2]; o1.w = (float)pv[3];
      o2.x = (float)pv[4]; o2.y = (float)pv[5]; o2.z = (float)pv[6]; o2.w = (float)pv[7];
      float4* dstp = reinterpret_cast<float4*>(attn_out + (size_t)(t0 + row) * T_DIM + s0 + col);
      dstp[0] = o1;
      dstp[1] = o2;
    }
#pragma unroll
    for (int ki = 0; ki < 4; ++ki) {
      bf16x8 aP0 = ld8(bufP, w * 32 + l16, ki * 32 + quad * 8);
      bf16x8 aP1 = ld8(bufP, w * 32 + 16 + l16, ki * 32 + quad * 8);
#pragma unroll
      for (int nt = 0; nt < 8; ++nt) {
        bf16x8 bW = ld8(bufB, nt * 16 + l16, ki * 32 + quad * 8);
        uacc[0][nt] = MFMA16(aP0, bW, uacc[0][nt], 0, 0, 0);
        uacc[1][nt] = MFMA16(aP1, bW, uacc[1][nt], 0, 0, 0);
      }
    }
  }

#pragma unroll
  for (int mt = 0; mt < 2; ++mt)
#pragma unroll
    for (int nt = 0; nt < 8; ++nt)
#pragma unroll
      for (int r = 0; r < 4; ++r)
        o_out[(size_t)(t0 + w * 32 + mt * 16 + quad * 4 + r) * D_DIM + nt * 16 + l16] =
            uacc[mt][nt][r];
}

extern "C" void kernel_launch(void* const* d_in, const int* in_sizes, int n_in,
                              void* d_out, int out_size, void* d_ws, size_t ws_size,
                              hipStream_t stream) {
  (void)in_sizes; (void)n_in; (void)out_size;
  const float* q_time    = (const float*)d_in[0];
  const float* k_time    = (const float*)d_in[1];
  const float* q_feature = (const float*)d_in[2];
  const float* k_feature = (const float*)d_in[3];
  const float* v         = (const float*)d_in[4];
  float* out = (float*)d_out;
  __bf16* wt = (__bf16*)d_ws;                         // WT[64][128][1024] bf16 = 16 MiB

  const size_t NELEM = (size_t)NHEAD * T_DIM * D_DIM; // 8388608
  const size_t WS_NEED = NELEM * 2 * 3;               // WT + qtb + ktb (48 MiB)

  if (ws_size >= WS_NEED) {
    __bf16* qtb = wt + NELEM;
    __bf16* ktb = qtb + NELEM;
    // feature (blocks 0-127) + qt/kt bf16 prep (blocks 128-383) in one launch
    cd_attn_feature<<<384, 256, 0, stream>>>(q_feature, k_feature, out,
                                             q_time, k_time, qtb, ktb);
    cd_attn_w<<<512, 256, 0, stream>>>(v, out, wt);
    cd_attn_time_v2<<<512, 256, 0, stream>>>(qtb, ktb, wt, out);
  } else {
    cd_attn_feature<<<128, 256, 0, stream>>>(q_feature, k_feature, out,
                                             nullptr, nullptr, nullptr, nullptr);
    cd_attn_w<<<512, 256, 0, stream>>>(v, out, wt);
    cd_attn_time<<<512, 256, 0, stream>>>(q_time, k_time, wt, out);
  }
}